// Round 1
// baseline (578.556 us; speedup 1.0000x reference)
//
#include <hip/hip_runtime.h>
#include <hip/hip_bf16.h>
#include <stdint.h>

// Problem constants
#define T_TOK 1024
#define D_DIM 2048
#define DFF   1024
#define NE    16
#define TOPK  6

typedef float f32x4 __attribute__((ext_vector_type(4)));
typedef __bf16 bf16x8 __attribute__((ext_vector_type(8)));
typedef unsigned short u16x8 __attribute__((ext_vector_type(8)));
typedef unsigned int u32x4 __attribute__((ext_vector_type(4)));

// RNE float -> bf16 (finite inputs only)
__device__ __forceinline__ unsigned short f2bf(float f) {
    union { float f; unsigned int u; } v; v.f = f;
    unsigned int x = v.u;
    unsigned int r = x + 0x7FFFu + ((x >> 16) & 1u);
    return (unsigned short)(r >> 16);
}

// HW packed cvt: lo16 = bf16(a), hi16 = bf16(b), RNE (matches f2bf)
__device__ __forceinline__ unsigned int pkbf(float a, float b) {
    unsigned int r;
    asm("v_cvt_pk_bf16_f32 %0, %1, %2" : "=v"(r) : "v"(a), "v"(b));
    return r;
}
__device__ __forceinline__ u16x8 pk8(f32x4 a, f32x4 b) {
    u32x4 r;
    r[0] = pkbf(a[0], a[1]); r[1] = pkbf(a[2], a[3]);
    r[2] = pkbf(b[0], b[1]); r[3] = pkbf(b[2], b[3]);
    return __builtin_bit_cast(u16x8, r);
}

// ---------------- streaming fp32 -> bf16 (x only) ----------------
__global__ void cvt_f32_bf16(const float* __restrict__ src,
                             unsigned short* __restrict__ dst, int n4) {
    int i = blockIdx.x * blockDim.x + threadIdx.x;
    int stride = gridDim.x * blockDim.x;
    for (; i < n4; i += stride) {
        float4 v = ((const float4*)src)[i];
        ushort4 o;
        o.x = f2bf(v.x); o.y = f2bf(v.y); o.z = f2bf(v.z); o.w = f2bf(v.w);
        ((ushort4*)dst)[i] = o;
    }
}

// ---------------- routing: single block, LDS, builds compact lists ----------
// Per expert: token list + per-slot combine weight; 128-aligned slab offsets
// (aoff) for compact hc/hc2 rows; per-token inverse index inv[t][j]=(e<<10)|p.
__global__ __launch_bounds__(1024)
void routing_kernel(const int* __restrict__ sel,    // [T, K]
                    const float* __restrict__ rw,   // [T, K]
                    float* __restrict__ cwl,        // [E, 1024] per-slot weight
                    int* __restrict__ list,         // [E, 1024] token ids
                    int* __restrict__ count,        // [E]
                    int* __restrict__ aoff,         // [E+1] 128-aligned offsets
                    int* __restrict__ inv) {        // [T, 8], -1 terminated
    __shared__ float scw[NE * T_TOK];   // 64 KB
    __shared__ int scount[NE];
    const int t = threadIdx.x;
#pragma unroll
    for (int e = 0; e < NE; ++e) scw[e * T_TOK + t] = 0.f;
    if (t < NE) scount[t] = 0;
    __syncthreads();
#pragma unroll
    for (int k = 0; k < TOPK; ++k) {
        int e = sel[t * TOPK + k];
        scw[e * T_TOK + t] += rw[t * TOPK + k];   // owner-thread RMW, safe
    }
    __syncthreads();
    int j = 0;
#pragma unroll
    for (int e = 0; e < NE; ++e) {
        float c = scw[e * T_TOK + t];
        if (c != 0.f) {
            int p = atomicAdd(&scount[e], 1);     // LDS atomic
            list[(e << 10) + p] = t;
            cwl [(e << 10) + p] = c;
            inv[t * 8 + j] = (e << 10) | p;
            ++j;
        }
    }
    for (; j < 8; ++j) inv[t * 8 + j] = -1;
    __syncthreads();
    if (t < NE) count[t] = scount[t];
    if (t == 0) {
        int o = 0;
#pragma unroll
        for (int e = 0; e < NE; ++e) { aoff[e] = o; o += (scount[e] + 127) & ~127; }
        aoff[NE] = o;
    }
}

// ---------------- GEMM1: fused gate+up+SwiGLU, fp32 weights fused-cvt -------
// A = gathered x rows (bf16), B0/B1 = w0/w1 rows loaded fp32 and converted to
// bf16 in registers (v_cvt_pk_bf16_f32) before the LDS write. Software
// pipelined: loads for k+1 issue between the barriers and stay in flight
// across compute (register loads don't drain at s_barrier).
__global__ __launch_bounds__(256, 2)
void gemm1_kernel(const unsigned short* __restrict__ xb,   // [T, D] bf16
                  const float* __restrict__ w0,            // [E, DFF, D] f32
                  const float* __restrict__ w1,            // [E, DFF, D] f32
                  const float* __restrict__ cwl,           // [E, 1024]
                  const int* __restrict__ list,            // [E, 1024]
                  const int* __restrict__ count,           // [E]
                  const int* __restrict__ aoff,            // [E+1]
                  const float* __restrict__ s0,
                  const float* __restrict__ s1,
                  const float* __restrict__ s2,
                  unsigned short* __restrict__ hc)         // [8192, DFF] bf16
{
    const int tf = blockIdx.x, tile = blockIdx.y, e = blockIdx.z;
    const int n_e = count[e];
    const int base = tile * 128;
    if (base >= n_e) return;
    const int rowbase = aoff[e] + base;

    const int tid = threadIdx.x;
    const int lane = tid & 63, wid = tid >> 6;
    const int wm = wid >> 1, wn = wid & 1;
    const int quad = lane >> 4, l16 = lane & 15;

    __shared__ alignas(16) unsigned short sA [128 * 64];
    __shared__ alignas(16) unsigned short sB0[128 * 64];
    __shared__ alignas(16) unsigned short sB1[128 * 64];
    __shared__ int   slist[128];
    __shared__ float cws[128];

    if (tid < 128) {
        int idx = base + tid;
        int cl = idx < n_e ? idx : (n_e - 1);     // clamp pads to a valid token
        slist[tid] = list[(e << 10) + cl];
        cws[tid] = (idx < n_e) ? cwl[(e << 10) + cl] : 0.f;  // pads -> 0
    }
    __syncthreads();

    // staging geometry: thread covers rows it*32 + (tid>>3), col group tid&7
    const int row0 = tid >> 3, col = tid & 7;
    const int cs = col ^ (row0 & 7);              // XOR swizzle (row&7 == row0&7)

    const float* w0e = w0 + (size_t)e * DFF * D_DIM;
    const float* w1e = w1 + (size_t)e * DFF * D_DIM;

    int iA[4], iB[4];
#pragma unroll
    for (int it = 0; it < 4; ++it) {
        int tok = slist[it * 32 + row0];
        iA[it] = tok * D_DIM + col * 8;
        iB[it] = (tf * 128 + it * 32 + row0) * D_DIM + col * 8;
    }

    f32x4 accG[4][4], accU[4][4];
    const f32x4 zz = {0.f, 0.f, 0.f, 0.f};
#pragma unroll
    for (int mi = 0; mi < 4; ++mi)
#pragma unroll
        for (int ni = 0; ni < 4; ++ni) { accG[mi][ni] = zz; accU[mi][ni] = zz; }

    u16x8 rA[4], cB0[4], cB1[4];
    f32x4 fB0[4][2], fB1[4][2];

    auto g1_load = [&](int K) {
#pragma unroll
        for (int it = 0; it < 4; ++it) {
            rA[it]     = *(const u16x8*)(xb + iA[it] + K);
            fB0[it][0] = *(const f32x4*)(w0e + iB[it] + K);
            fB0[it][1] = *(const f32x4*)(w0e + iB[it] + K + 4);
            fB1[it][0] = *(const f32x4*)(w1e + iB[it] + K);
            fB1[it][1] = *(const f32x4*)(w1e + iB[it] + K + 4);
        }
    };
    auto g1_cvt = [&]() {
#pragma unroll
        for (int it = 0; it < 4; ++it) {
            cB0[it] = pk8(fB0[it][0], fB0[it][1]);
            cB1[it] = pk8(fB1[it][0], fB1[it][1]);
        }
    };

    g1_load(0); g1_cvt();

    for (int k0 = 0; k0 < D_DIM; k0 += 64) {
        __syncthreads();   // prev K-step compute done before LDS overwrite
#pragma unroll
        for (int it = 0; it < 4; ++it) {
            int r = it * 32 + row0;
            *(u16x8*)(sA  + r * 64 + cs * 8) = rA[it];
            *(u16x8*)(sB0 + r * 64 + cs * 8) = cB0[it];
            *(u16x8*)(sB1 + r * 64 + cs * 8) = cB1[it];
        }
        const int k1 = k0 + 64;
        if (k1 < D_DIM) g1_load(k1);   // in flight across compute
        __syncthreads();
#pragma unroll
        for (int kk = 0; kk < 2; ++kk) {
            bf16x8 af[4];
#pragma unroll
            for (int mi = 0; mi < 4; ++mi) {
                int row = wm * 64 + mi * 16 + l16;
                int cch = (kk * 4 + quad) ^ (row & 7);
                af[mi] = __builtin_bit_cast(bf16x8,
                         *(const u16x8*)(sA + row * 64 + cch * 8));
            }
#pragma unroll
            for (int ni = 0; ni < 4; ++ni) {
                int row = wn * 64 + ni * 16 + l16;
                int cch = (kk * 4 + quad) ^ (row & 7);
                bf16x8 b0 = __builtin_bit_cast(bf16x8,
                            *(const u16x8*)(sB0 + row * 64 + cch * 8));
                bf16x8 b1 = __builtin_bit_cast(bf16x8,
                            *(const u16x8*)(sB1 + row * 64 + cch * 8));
#pragma unroll
                for (int mi = 0; mi < 4; ++mi) {
                    accG[mi][ni] = __builtin_amdgcn_mfma_f32_16x16x32_bf16(
                        af[mi], b0, accG[mi][ni], 0, 0, 0);
                    accU[mi][ni] = __builtin_amdgcn_mfma_f32_16x16x32_bf16(
                        af[mi], b1, accU[mi][ni], 0, 0, 0);
                }
            }
        }
        if (k1 < D_DIM) g1_cvt();      // vmcnt wait lands here, after compute
    }

    const float s0e = s0[e], s1e = s1[e], s2e = s2[e];
#pragma unroll
    for (int mi = 0; mi < 4; ++mi) {
#pragma unroll
        for (int reg = 0; reg < 4; ++reg) {
            int tl = wm * 64 + mi * 16 + quad * 4 + reg;   // C/D row = quad*4+reg
            float cwt = cws[tl] * s2e;                      // 0 for padded rows
            size_t slot = (size_t)(rowbase + tl);
#pragma unroll
            for (int ni = 0; ni < 4; ++ni) {
                float g = accG[mi][ni][reg] * s0e;
                float u = accU[mi][ni][reg] * s1e;
                float h = g / (1.f + __expf(-g)) * u;      // silu(g)*u
                int fc = tf * 128 + wn * 64 + ni * 16 + l16;  // C/D col = lane&15
                hc[slot * DFF + fc] = f2bf(h * cwt);
            }
        }
    }
}

// ---------------- GEMM2: down projection, fp32 w2 fused-cvt, compact out ----
// A = compact hc rows (bf16, contiguous, no gather), B = w2 fp32 -> bf16 in
// registers. Output: compact f32 slab hc2 (plain stores, no atomics).
__global__ __launch_bounds__(256, 3)
void gemm2_kernel(const unsigned short* __restrict__ hc,   // [8192, DFF] bf16
                  const float* __restrict__ w2,            // [E, D, DFF] f32
                  const int* __restrict__ count,
                  const int* __restrict__ aoff,
                  float* __restrict__ hc2)                 // [8192, D] f32
{
    const int td = blockIdx.x, tile = blockIdx.y, e = blockIdx.z;
    const int n_e = count[e];
    const int base = tile * 128;
    if (base >= n_e) return;
    const int rowbase = aoff[e] + base;

    const int tid = threadIdx.x;
    const int lane = tid & 63, wid = tid >> 6;
    const int wm = wid >> 1, wn = wid & 1;
    const int quad = lane >> 4, l16 = lane & 15;

    __shared__ alignas(16) unsigned short sA[128 * 64];
    __shared__ alignas(16) unsigned short sB[128 * 64];

    const int row0 = tid >> 3, col = tid & 7;
    const int cs = col ^ (row0 & 7);

    const float* w2e = w2 + (size_t)e * D_DIM * DFF;

    int iA[4], iB[4];
#pragma unroll
    for (int it = 0; it < 4; ++it) {
        iA[it] = (rowbase + it * 32 + row0) * DFF + col * 8;
        iB[it] = (td * 128 + it * 32 + row0) * DFF + col * 8;
    }

    f32x4 acc[4][4];
    const f32x4 zz = {0.f, 0.f, 0.f, 0.f};
#pragma unroll
    for (int mi = 0; mi < 4; ++mi)
#pragma unroll
        for (int ni = 0; ni < 4; ++ni) acc[mi][ni] = zz;

    u16x8 rA[4], cB[4];
    f32x4 fB[4][2];

    auto g2_load = [&](int K) {
#pragma unroll
        for (int it = 0; it < 4; ++it) {
            rA[it]    = *(const u16x8*)(hc + iA[it] + K);
            fB[it][0] = *(const f32x4*)(w2e + iB[it] + K);
            fB[it][1] = *(const f32x4*)(w2e + iB[it] + K + 4);
        }
    };
    auto g2_cvt = [&]() {
#pragma unroll
        for (int it = 0; it < 4; ++it) cB[it] = pk8(fB[it][0], fB[it][1]);
    };

    g2_load(0); g2_cvt();

    for (int k0 = 0; k0 < DFF; k0 += 64) {
        __syncthreads();
#pragma unroll
        for (int it = 0; it < 4; ++it) {
            int r = it * 32 + row0;
            *(u16x8*)(sA + r * 64 + cs * 8) = rA[it];
            *(u16x8*)(sB + r * 64 + cs * 8) = cB[it];
        }
        const int k1 = k0 + 64;
        if (k1 < DFF) g2_load(k1);
        __syncthreads();
#pragma unroll
        for (int kk = 0; kk < 2; ++kk) {
            bf16x8 af[4];
#pragma unroll
            for (int mi = 0; mi < 4; ++mi) {
                int row = wm * 64 + mi * 16 + l16;
                int cch = (kk * 4 + quad) ^ (row & 7);
                af[mi] = __builtin_bit_cast(bf16x8,
                         *(const u16x8*)(sA + row * 64 + cch * 8));
            }
#pragma unroll
            for (int ni = 0; ni < 4; ++ni) {
                int row = wn * 64 + ni * 16 + l16;
                int cch = (kk * 4 + quad) ^ (row & 7);
                bf16x8 bfr = __builtin_bit_cast(bf16x8,
                             *(const u16x8*)(sB + row * 64 + cch * 8));
#pragma unroll
                for (int mi = 0; mi < 4; ++mi)
                    acc[mi][ni] = __builtin_amdgcn_mfma_f32_16x16x32_bf16(
                        af[mi], bfr, acc[mi][ni], 0, 0, 0);
            }
        }
        if (k1 < DFF) g2_cvt();
    }

#pragma unroll
    for (int mi = 0; mi < 4; ++mi)
#pragma unroll
        for (int reg = 0; reg < 4; ++reg) {
            int tl = wm * 64 + mi * 16 + quad * 4 + reg;
            float* orow = hc2 + (size_t)(rowbase + tl) * D_DIM;
#pragma unroll
            for (int ni = 0; ni < 4; ++ni) {
                int d = td * 128 + wn * 64 + ni * 16 + l16;
                orow[d] = acc[mi][ni][reg];   // pads write junk rows, never read
            }
        }
}

// ---------------- combine: per-token gather of <=6 expert rows --------------
__global__ __launch_bounds__(256)
void combine_kernel(const float* __restrict__ hc2,   // [8192, D] f32
                    const int* __restrict__ inv,     // [T, 8]
                    const int* __restrict__ aoff,    // [E+1]
                    float* __restrict__ out)         // [T, D]
{
    const int t = blockIdx.x, tid = threadIdx.x;
    __shared__ int rows[8];
    if (tid < 8) {
        int v = inv[t * 8 + tid];
        rows[tid] = (v < 0) ? -1 : (aoff[v >> 10] + (v & 1023));
    }
    __syncthreads();
    const int d0 = tid * 8;
    f32x4 a0 = {0.f, 0.f, 0.f, 0.f}, a1 = a0;
    for (int j = 0; j < 8; ++j) {
        int r = rows[j];
        if (r < 0) break;
        const f32x4* p = (const f32x4*)(hc2 + (size_t)r * D_DIM + d0);
        a0 += p[0]; a1 += p[1];
    }
    f32x4* o = (f32x4*)(out + (size_t)t * D_DIM + d0);
    o[0] = a0; o[1] = a1;
}

// ---------------- launch ----------------

extern "C" void kernel_launch(void* const* d_in, const int* in_sizes, int n_in,
                              void* d_out, int out_size, void* d_ws, size_t ws_size,
                              hipStream_t stream) {
    const float* x  = (const float*)d_in[0];
    const float* w0 = (const float*)d_in[1];
    const float* w1 = (const float*)d_in[2];
    const float* w2 = (const float*)d_in[3];
    const float* s0 = (const float*)d_in[4];
    const float* s1 = (const float*)d_in[5];
    const float* s2 = (const float*)d_in[6];
    const int*   sel = (const int*)d_in[7];
    const float* rw = (const float*)d_in[8];
    float* out = (float*)d_out;

    char* ws = (char*)d_ws;
    // compact layout (~88.2 MB total):
    constexpr size_t HC2_OFF  = 0;                       // 8192*2048*4 = 67,108,864
    constexpr size_t HC_OFF   = 67108864ull;             // 8192*1024*2 = 16,777,216
    constexpr size_t XB_OFF   = 83886080ull;             //  4,194,304
    constexpr size_t LIST_OFF = 88080384ull;             //     65,536
    constexpr size_t CWL_OFF  = 88145920ull;             //     65,536
    constexpr size_t CNT_OFF  = 88211456ull;             //        256
    constexpr size_t AOFF_OFF = 88211712ull;             //        256
    constexpr size_t INV_OFF  = 88211968ull;             //     32,768
    float*          hc2   = (float*)         (ws + HC2_OFF);
    unsigned short* hc    = (unsigned short*)(ws + HC_OFF);
    unsigned short* xb    = (unsigned short*)(ws + XB_OFF);
    int*            list  = (int*)           (ws + LIST_OFF);
    float*          cwl   = (float*)         (ws + CWL_OFF);
    int*            count = (int*)           (ws + CNT_OFF);
    int*            aoff  = (int*)           (ws + AOFF_OFF);
    int*            inv   = (int*)           (ws + INV_OFF);

    // 1. routing (lists, per-slot weights, aligned offsets, inverse index)
    routing_kernel<<<1, 1024, 0, stream>>>(sel, rw, cwl, list, count, aoff, inv);

    // 2. x -> bf16 (small; weights convert in-GEMM)
    cvt_f32_bf16<<<2048, 256, 0, stream>>>(x, xb, T_TOK * D_DIM / 4);

    // 3. fused gate/up/SwiGLU (fp32 w0/w1 staged + converted in-kernel)
    gemm1_kernel<<<dim3(DFF / 128, T_TOK / 128, NE), 256, 0, stream>>>(
        xb, w0, w1, cwl, list, count, aoff, s0, s1, s2, hc);

    // 4. down projection -> compact f32 slab (no atomics)
    gemm2_kernel<<<dim3(D_DIM / 128, T_TOK / 128, NE), 256, 0, stream>>>(
        hc, w2, count, aoff, hc2);

    // 5. per-token combine (replaces memset + atomic scatter)
    combine_kernel<<<T_TOK, 256, 0, stream>>>(hc2, inv, aoff, out);
}

// Round 3
// 555.387 us; speedup vs baseline: 1.0417x; 1.0417x over previous
//
#include <hip/hip_runtime.h>
#include <hip/hip_bf16.h>
#include <stdint.h>

// Problem constants
#define T_TOK 1024
#define D_DIM 2048
#define DFF   1024
#define NE    16
#define TOPK  6

typedef float f32x4 __attribute__((ext_vector_type(4)));
typedef __bf16 bf16x8 __attribute__((ext_vector_type(8)));
typedef unsigned short u16x8 __attribute__((ext_vector_type(8)));

// RNE float -> bf16 (finite inputs only)
__device__ __forceinline__ unsigned short f2bf(float f) {
    union { float f; unsigned int u; } v; v.f = f;
    unsigned int x = v.u;
    unsigned int r = x + 0x7FFFu + ((x >> 16) & 1u);
    return (unsigned short)(r >> 16);
}

// async global->LDS, 16B per lane. LDS dest: wave-uniform base + lane*16;
// global src is per-lane.
typedef __attribute__((address_space(1))) const unsigned int gas_u32;
typedef __attribute__((address_space(3))) unsigned int las_u32;
__device__ __forceinline__ void gload16(const void* g, void* l) {
    __builtin_amdgcn_global_load_lds((gas_u32*)g, (las_u32*)l, 16, 0, 0);
}

// ---------------- fused streaming fp32 -> bf16 (x, w0, w1) -----------------
__global__ __launch_bounds__(256)
void cvt3(const float* __restrict__ x,  const float* __restrict__ w0,
          const float* __restrict__ w1,
          unsigned short* __restrict__ xb, unsigned short* __restrict__ w0b,
          unsigned short* __restrict__ w1b) {
    const long NX = (long)T_TOK * D_DIM / 4;        // 524288 float4
    const long NW = (long)NE * DFF * D_DIM / 4;     // 8388608 float4
    const long total = NX + 2 * NW;
    long i = (long)blockIdx.x * blockDim.x + threadIdx.x;
    const long stride = (long)gridDim.x * blockDim.x;
    for (; i < total; i += stride) {
        const float4* s; ushort4* d; long j;
        if (i < NX)           { s = (const float4*)x;  d = (ushort4*)xb;  j = i; }
        else if (i < NX + NW) { s = (const float4*)w0; d = (ushort4*)w0b; j = i - NX; }
        else                  { s = (const float4*)w1; d = (ushort4*)w1b; j = i - NX - NW; }
        float4 v = s[j];
        ushort4 o;
        o.x = f2bf(v.x); o.y = f2bf(v.y); o.z = f2bf(v.z); o.w = f2bf(v.w);
        d[j] = o;
    }
}

__global__ __launch_bounds__(256)
void cvt1(const float* __restrict__ src, unsigned short* __restrict__ dst, long n4) {
    long i = (long)blockIdx.x * blockDim.x + threadIdx.x;
    const long stride = (long)gridDim.x * blockDim.x;
    for (; i < n4; i += stride) {
        float4 v = ((const float4*)src)[i];
        ushort4 o;
        o.x = f2bf(v.x); o.y = f2bf(v.y); o.z = f2bf(v.z); o.w = f2bf(v.w);
        ((ushort4*)dst)[i] = o;
    }
}

// ---------------- routing: single block, LDS, builds compact lists ----------
__global__ __launch_bounds__(1024)
void routing_kernel(const int* __restrict__ sel,    // [T, K]
                    const float* __restrict__ rw,   // [T, K]
                    float* __restrict__ cwl,        // [E, 1024] per-slot weight
                    int* __restrict__ list,         // [E, 1024] token ids
                    int* __restrict__ count,        // [E]
                    int* __restrict__ aoff,         // [E+1] 128-aligned offsets
                    int* __restrict__ inv) {        // [T, 8], -1 terminated
    __shared__ float scw[NE * T_TOK];   // 64 KB
    __shared__ int scount[NE];
    const int t = threadIdx.x;
#pragma unroll
    for (int e = 0; e < NE; ++e) scw[e * T_TOK + t] = 0.f;
    if (t < NE) scount[t] = 0;
    __syncthreads();
#pragma unroll
    for (int k = 0; k < TOPK; ++k) {
        int e = sel[t * TOPK + k];
        scw[e * T_TOK + t] += rw[t * TOPK + k];   // owner-thread RMW, safe
    }
    __syncthreads();
    int j = 0;
#pragma unroll
    for (int e = 0; e < NE; ++e) {
        float c = scw[e * T_TOK + t];
        if (c != 0.f) {
            int p = atomicAdd(&scount[e], 1);     // LDS atomic
            list[(e << 10) + p] = t;
            cwl [(e << 10) + p] = c;
            inv[t * 8 + j] = (e << 10) | p;
            ++j;
        }
    }
    for (; j < 8; ++j) inv[t * 8 + j] = -1;
    __syncthreads();
    if (t < NE) count[t] = scount[t];
    if (t == 0) {
        int o = 0;
#pragma unroll
        for (int e = 0; e < NE; ++e) { aoff[e] = o; o += (scount[e] + 127) & ~127; }
        aoff[NE] = o;
    }
}

// ---------------- GEMM1: fused gate+up+SwiGLU -------------------------------
// Tile 128(M) x 64(N), BK=64, single-buffered LDS (33KB -> 3 blocks/CU),
// m97 order: STAGE -> sync -> compute -> sync. global_load_lds with
// pre-swizzled global source (involution applied on source AND read).
__global__ __launch_bounds__(256, 3)
void gemm1_kernel(const unsigned short* __restrict__ xb,   // [T, D] bf16
                  const unsigned short* __restrict__ wb0,  // [E, DFF, D] bf16
                  const unsigned short* __restrict__ wb1,  // [E, DFF, D] bf16
                  const float* __restrict__ cwl,           // [E, 1024]
                  const int* __restrict__ list,            // [E, 1024]
                  const int* __restrict__ count,           // [E]
                  const int* __restrict__ aoff,            // [E+1]
                  const float* __restrict__ s0,
                  const float* __restrict__ s1,
                  const float* __restrict__ s2,
                  unsigned short* __restrict__ hc)         // [8192, DFF] bf16
{
    const int tf = blockIdx.x, tile = blockIdx.y, e = blockIdx.z;
    const int n_e = count[e];
    const int base = tile * 128;
    if (base >= n_e) return;
    const int rowbase = aoff[e] + base;

    const int tid = threadIdx.x;
    const int lane = tid & 63, wid = tid >> 6;
    const int wm = wid >> 1, wn = wid & 1;
    const int quad = lane >> 4, l16 = lane & 15;

    __shared__ alignas(16) unsigned short sA [128 * 64];   // 16 KB
    __shared__ alignas(16) unsigned short sB0[64 * 64];    //  8 KB
    __shared__ alignas(16) unsigned short sB1[64 * 64];    //  8 KB
    __shared__ int   slist[128];
    __shared__ float cws[128];

    if (tid < 128) {
        int idx = base + tid;
        int cl = idx < n_e ? idx : (n_e - 1);     // clamp pads to a valid token
        slist[tid] = list[(e << 10) + cl];
        cws[tid] = (idx < n_e) ? cwl[(e << 10) + cl] : 0.f;  // pads -> 0
    }
    __syncthreads();

    // staging: lane l covers row_in_group = l>>3, col-block (l&7); source
    // col-block XOR-swizzled so LDS[row][c] = G[row][c ^ (row&7)].
    const int lr = lane >> 3, lc = lane & 7;
    const int sw = lc ^ lr;                        // involution (rows 8-aligned)

    const unsigned short* w0e = wb0 + ((size_t)e * DFF + tf * 64) * D_DIM;
    const unsigned short* w1e = wb1 + ((size_t)e * DFF + tf * 64) * D_DIM;

    // A: 128 rows -> 4 wave-loads/wave. B0/B1: 64 rows -> 2 each.
    const unsigned short* gA[4]; int loA[4];
    const unsigned short* gB0[2]; const unsigned short* gB1[2]; int loB[2];
#pragma unroll
    for (int j = 0; j < 4; ++j) {
        int r = wid * 32 + j * 8;
        int tok = slist[r + lr];
        gA[j] = xb + (size_t)tok * D_DIM + sw * 8;
        loA[j] = r * 64;
    }
#pragma unroll
    for (int j = 0; j < 2; ++j) {
        int r = wid * 16 + j * 8;
        gB0[j] = w0e + (size_t)(r + lr) * D_DIM + sw * 8;
        gB1[j] = w1e + (size_t)(r + lr) * D_DIM + sw * 8;
        loB[j] = r * 64;
    }

    f32x4 accG[4][2], accU[4][2];
    const f32x4 zz = {0.f, 0.f, 0.f, 0.f};
#pragma unroll
    for (int mi = 0; mi < 4; ++mi)
#pragma unroll
        for (int ni = 0; ni < 2; ++ni) { accG[mi][ni] = zz; accU[mi][ni] = zz; }

    for (int k0 = 0; k0 < D_DIM; k0 += 64) {
#pragma unroll
        for (int j = 0; j < 4; ++j) gload16(gA[j] + k0, sA + loA[j]);
#pragma unroll
        for (int j = 0; j < 2; ++j) {
            gload16(gB0[j] + k0, sB0 + loB[j]);
            gload16(gB1[j] + k0, sB1 + loB[j]);
        }
        __syncthreads();                           // drain staging
#pragma unroll
        for (int kk = 0; kk < 2; ++kk) {
            bf16x8 af[4], b0f[2], b1f[2];
#pragma unroll
            for (int mi = 0; mi < 4; ++mi) {
                int row = wm * 64 + mi * 16 + l16;
                int cch = (kk * 4 + quad) ^ (row & 7);
                af[mi] = __builtin_bit_cast(bf16x8,
                         *(const u16x8*)(sA + row * 64 + cch * 8));
            }
#pragma unroll
            for (int ni = 0; ni < 2; ++ni) {
                int row = wn * 32 + ni * 16 + l16;
                int cch = (kk * 4 + quad) ^ (row & 7);
                b0f[ni] = __builtin_bit_cast(bf16x8,
                          *(const u16x8*)(sB0 + row * 64 + cch * 8));
                b1f[ni] = __builtin_bit_cast(bf16x8,
                          *(const u16x8*)(sB1 + row * 64 + cch * 8));
            }
#pragma unroll
            for (int mi = 0; mi < 4; ++mi)
#pragma unroll
                for (int ni = 0; ni < 2; ++ni) {
                    accG[mi][ni] = __builtin_amdgcn_mfma_f32_16x16x32_bf16(
                        af[mi], b0f[ni], accG[mi][ni], 0, 0, 0);
                    accU[mi][ni] = __builtin_amdgcn_mfma_f32_16x16x32_bf16(
                        af[mi], b1f[ni], accU[mi][ni], 0, 0, 0);
                }
        }
        __syncthreads();                           // compute done before refill
    }

    const float s0e = s0[e], s1e = s1[e], s2e = s2[e];
#pragma unroll
    for (int mi = 0; mi < 4; ++mi) {
#pragma unroll
        for (int reg = 0; reg < 4; ++reg) {
            int tl = wm * 64 + mi * 16 + quad * 4 + reg;   // C/D row = quad*4+reg
            float cwt = cws[tl] * s2e;                      // 0 for padded rows
            size_t slot = (size_t)(rowbase + tl);
#pragma unroll
            for (int ni = 0; ni < 2; ++ni) {
                float g = accG[mi][ni][reg] * s0e;
                float u = accU[mi][ni][reg] * s1e;
                float h = g / (1.f + __expf(-g)) * u;      // silu(g)*u
                int fc = tf * 64 + wn * 32 + ni * 16 + l16;   // C/D col = lane&15
                hc[slot * DFF + fc] = f2bf(h * cwt);
            }
        }
    }
}

// ---------------- GEMM2: down projection, compact out -----------------------
// Tile 128x128, BK=64, single-buffered (32KB LDS -> 3 blocks/CU), m97 order.
__global__ __launch_bounds__(256, 3)
void gemm2_kernel(const unsigned short* __restrict__ hc,   // [8192, DFF] bf16
                  const unsigned short* __restrict__ wb2,  // [E, D, DFF] bf16
                  const int* __restrict__ count,
                  const int* __restrict__ aoff,
                  float* __restrict__ hc2)                 // [8192, D] f32
{
    const int td = blockIdx.x, tile = blockIdx.y, e = blockIdx.z;
    const int n_e = count[e];
    const int base = tile * 128;
    if (base >= n_e) return;
    const int rowbase = aoff[e] + base;

    const int tid = threadIdx.x;
    const int lane = tid & 63, wid = tid >> 6;
    const int wm = wid >> 1, wn = wid & 1;
    const int quad = lane >> 4, l16 = lane & 15;

    __shared__ alignas(16) unsigned short sA[128 * 64];    // 16 KB
    __shared__ alignas(16) unsigned short sB[128 * 64];    // 16 KB

    const int lr = lane >> 3, lc = lane & 7;
    const int sw = lc ^ lr;

    const unsigned short* a_base = hc  + (size_t)rowbase * DFF;
    const unsigned short* b_base = wb2 + ((size_t)e * D_DIM + td * 128) * DFF;

    const unsigned short* gA[4]; const unsigned short* gB[4];
    int ldso[4];
#pragma unroll
    for (int j = 0; j < 4; ++j) {
        int r = wid * 32 + j * 8;
        gA[j] = a_base + (size_t)(r + lr) * DFF + sw * 8;
        gB[j] = b_base + (size_t)(r + lr) * DFF + sw * 8;
        ldso[j] = r * 64;
    }

    f32x4 acc[4][4];
    const f32x4 zz = {0.f, 0.f, 0.f, 0.f};
#pragma unroll
    for (int mi = 0; mi < 4; ++mi)
#pragma unroll
        for (int ni = 0; ni < 4; ++ni) acc[mi][ni] = zz;

    for (int k0 = 0; k0 < DFF; k0 += 64) {
#pragma unroll
        for (int j = 0; j < 4; ++j) {
            gload16(gA[j] + k0, sA + ldso[j]);
            gload16(gB[j] + k0, sB + ldso[j]);
        }
        __syncthreads();
#pragma unroll
        for (int kk = 0; kk < 2; ++kk) {
            bf16x8 af[4], bfr[4];
#pragma unroll
            for (int mi = 0; mi < 4; ++mi) {
                int row = wm * 64 + mi * 16 + l16;
                int cch = (kk * 4 + quad) ^ (row & 7);
                af[mi] = __builtin_bit_cast(bf16x8,
                         *(const u16x8*)(sA + row * 64 + cch * 8));
            }
#pragma unroll
            for (int ni = 0; ni < 4; ++ni) {
                int row = wn * 64 + ni * 16 + l16;
                int cch = (kk * 4 + quad) ^ (row & 7);
                bfr[ni] = __builtin_bit_cast(bf16x8,
                          *(const u16x8*)(sB + row * 64 + cch * 8));
            }
#pragma unroll
            for (int mi = 0; mi < 4; ++mi)
#pragma unroll
                for (int ni = 0; ni < 4; ++ni)
                    acc[mi][ni] = __builtin_amdgcn_mfma_f32_16x16x32_bf16(
                        af[mi], bfr[ni], acc[mi][ni], 0, 0, 0);
        }
        __syncthreads();
    }

#pragma unroll
    for (int mi = 0; mi < 4; ++mi)
#pragma unroll
        for (int reg = 0; reg < 4; ++reg) {
            int tl = wm * 64 + mi * 16 + quad * 4 + reg;
            float* orow = hc2 + (size_t)(rowbase + tl) * D_DIM;
#pragma unroll
            for (int ni = 0; ni < 4; ++ni) {
                int d = td * 128 + wn * 64 + ni * 16 + l16;
                orow[d] = acc[mi][ni][reg];   // pads write junk rows, never read
            }
        }
}

// ---------------- combine: per-token gather of <=6 expert rows --------------
__global__ __launch_bounds__(256)
void combine_kernel(const float* __restrict__ hc2,   // [8192, D] f32
                    const int* __restrict__ inv,     // [T, 8]
                    const int* __restrict__ aoff,    // [E+1]
                    float* __restrict__ out)         // [T, D]
{
    const int t = blockIdx.x, tid = threadIdx.x;
    __shared__ int rows[8];
    if (tid < 8) {
        int v = inv[t * 8 + tid];
        rows[tid] = (v < 0) ? -1 : (aoff[v >> 10] + (v & 1023));
    }
    __syncthreads();
    const int d0 = tid * 8;
    f32x4 a0 = {0.f, 0.f, 0.f, 0.f}, a1 = a0;
    for (int j = 0; j < 8; ++j) {
        int r = rows[j];
        if (r < 0) break;
        const f32x4* p = (const f32x4*)(hc2 + (size_t)r * D_DIM + d0);
        a0 += p[0]; a1 += p[1];
    }
    f32x4* o = (f32x4*)(out + (size_t)t * D_DIM + d0);
    o[0] = a0; o[1] = a1;
}

// ---------------- launch ----------------

extern "C" void kernel_launch(void* const* d_in, const int* in_sizes, int n_in,
                              void* d_out, int out_size, void* d_ws, size_t ws_size,
                              hipStream_t stream) {
    const float* x  = (const float*)d_in[0];
    const float* w0 = (const float*)d_in[1];
    const float* w1 = (const float*)d_in[2];
    const float* w2 = (const float*)d_in[3];
    const float* s0 = (const float*)d_in[4];
    const float* s1 = (const float*)d_in[5];
    const float* s2 = (const float*)d_in[6];
    const int*   sel = (const int*)d_in[7];
    const float* rw = (const float*)d_in[8];
    float* out = (float*)d_out;

    char* ws = (char*)d_ws;
    // layout, 155.4 MB total (sizes in BYTES; bf16 weight buf = 64 MiB each).
    // After gemm1: w2b aliases w0b (exact 67,108,864), hc2 aliases w1b (exact).
    constexpr size_t XB_OFF   = 0;                        //  4,194,304
    constexpr size_t W0B_OFF  = 4194304ull;               // 67,108,864
    constexpr size_t W1B_OFF  = 71303168ull;              // 67,108,864
    constexpr size_t HC_OFF   = 138412032ull;             // 16,777,216
    constexpr size_t LIST_OFF = 155189248ull;             //     65,536
    constexpr size_t CWL_OFF  = 155254784ull;             //     65,536
    constexpr size_t CNT_OFF  = 155320320ull;             //        256
    constexpr size_t AOFF_OFF = 155320576ull;             //        256
    constexpr size_t INV_OFF  = 155320832ull;             //     32,768
    unsigned short* xb    = (unsigned short*)(ws + XB_OFF);
    unsigned short* w0b   = (unsigned short*)(ws + W0B_OFF);
    unsigned short* w1b   = (unsigned short*)(ws + W1B_OFF);
    unsigned short* w2b   = (unsigned short*)(ws + W0B_OFF);  // alias (dead w0b)
    unsigned short* hc    = (unsigned short*)(ws + HC_OFF);
    float*          hc2   = (float*)         (ws + W1B_OFF);  // alias (dead w1b)
    int*            list  = (int*)           (ws + LIST_OFF);
    float*          cwl   = (float*)         (ws + CWL_OFF);
    int*            count = (int*)           (ws + CNT_OFF);
    int*            aoff  = (int*)           (ws + AOFF_OFF);
    int*            inv   = (int*)           (ws + INV_OFF);

    // 1. routing (lists, per-slot weights, aligned offsets, inverse index)
    routing_kernel<<<1, 1024, 0, stream>>>(sel, rw, cwl, list, count, aoff, inv);

    // 2. x, w0, w1 -> bf16 (one streaming pass)
    cvt3<<<2048, 256, 0, stream>>>(x, w0, w1, xb, w0b, w1b);

    // 3. fused gate/up/SwiGLU -> compact hc (cw*s2 folded in)
    gemm1_kernel<<<dim3(DFF / 64, T_TOK / 128, NE), 256, 0, stream>>>(
        xb, w0b, w1b, cwl, list, count, aoff, s0, s1, s2, hc);

    // 4. w2 -> bf16 into dead w0b region
    cvt1<<<2048, 256, 0, stream>>>(w2, w2b, (long)NE * D_DIM * DFF / 4);

    // 5. down projection -> compact f32 slab (no atomics), aliases dead w1b
    gemm2_kernel<<<dim3(D_DIM / 128, T_TOK / 128, NE), 256, 0, stream>>>(
        hc, w2b, count, aoff, hc2);

    // 6. per-token combine
    combine_kernel<<<T_TOK, 256, 0, stream>>>(hc2, inv, aoff, out);
}